// Round 5
// baseline (508.850 us; speedup 1.0000x reference)
//
#include <hip/hip_runtime.h>
#include <hip/hip_bf16.h>

// ---------------------------------------------------------------------------
// Attention block, N=8192 D=1024 (inputs fp32 or bf16, runtime-detected;
// OUTPUT IS FLOAT32 — the round-1..4 failure was writing bf16 into an
// fp32-read d_out):
//   qkv = x @ Wqkv ; S = q k^T / 32 (causal) ; P = softmax(S) ; O = P v
//   out = O @ Wout + bout
// Softmax without max-subtraction (S ~ N(0,1)); exp arg clamped, divide
// guarded (NaN-proof). E = exp(S) packed lower-triangular bf16; rowsums via
// ones-MFMA inside PV. All matmuls: 128x128 tile, 256 thr (2x2 waves),
// BK=32, explicit ds_write_b128 staging, v_mfma_f32_16x16x32_bf16.
// Input pointers selected BY ELEMENT COUNT (immune to d_in ordering).
// ---------------------------------------------------------------------------

typedef __bf16 v8bf __attribute__((ext_vector_type(8)));
typedef float  v4f  __attribute__((ext_vector_type(4)));

struct __align__(8) S4 { short x, y, z, w; };

__device__ inline short f2bf(float f) {
  __hip_bfloat16 h = __float2bfloat16(f);
  return *reinterpret_cast<short*>(&h);
}
__device__ inline float bf2f(short s) {
  unsigned u = ((unsigned)(unsigned short)s) << 16;
  float f;
  __builtin_memcpy(&f, &u, 4);
  return f;
}

// Stage a 128x32 bf16 tile (row-major, leading dim ldg) into LDS [128][32].
// Explicit path: coalesced 16B global loads -> ds_write_b128.
__device__ inline void stage_tile(const short* gbase, int ldg, short* lds, int tid) {
#pragma unroll
  for (int p = 0; p < 2; ++p) {
    const int c = p * 256 + tid;
    const v8bf val = *(const v8bf*)(gbase + (size_t)(c >> 2) * ldg + (c & 3) * 8);
    *(v8bf*)(lds + c * 8) = val;
  }
}

// One BK=32 step: 8 ds_read_b128 + 16 MFMA.
__device__ inline void mma_step(const short* As, const short* Bs, v4f acc[4][4],
                                int lane, int wm, int wn) {
  const int qd = lane >> 4, r16 = lane & 15;
  const short* ab = As + (wm * 64 + r16) * 32 + qd * 8;
  const short* bb = Bs + (wn * 64 + r16) * 32 + qd * 8;
  v8bf a[4], b[4];
#pragma unroll
  for (int t = 0; t < 4; ++t) {
    a[t] = *(const v8bf*)(ab + t * 512);
    b[t] = *(const v8bf*)(bb + t * 512);
  }
#pragma unroll
  for (int mt = 0; mt < 4; ++mt)
#pragma unroll
    for (int nt = 0; nt < 4; ++nt)
      acc[mt][nt] = __builtin_amdgcn_mfma_f32_16x16x32_bf16(a[mt], b[nt], acc[mt][nt], 0, 0, 0);
}

// PV variant: also accumulates row-sums via MFMA against all-ones B.
__device__ inline void mma_step_pv(const short* As, const short* Bs, v4f acc[4][4],
                                   v4f lacc[4], v8bf ones, int lane, int wm, int wn) {
  const int qd = lane >> 4, r16 = lane & 15;
  const short* ab = As + (wm * 64 + r16) * 32 + qd * 8;
  const short* bb = Bs + (wn * 64 + r16) * 32 + qd * 8;
  v8bf a[4], b[4];
#pragma unroll
  for (int t = 0; t < 4; ++t) {
    a[t] = *(const v8bf*)(ab + t * 512);
    b[t] = *(const v8bf*)(bb + t * 512);
  }
#pragma unroll
  for (int mt = 0; mt < 4; ++mt)
    lacc[mt] = __builtin_amdgcn_mfma_f32_16x16x32_bf16(a[mt], ones, lacc[mt], 0, 0, 0);
#pragma unroll
  for (int mt = 0; mt < 4; ++mt)
#pragma unroll
    for (int nt = 0; nt < 4; ++nt)
      acc[mt][nt] = __builtin_amdgcn_mfma_f32_16x16x32_bf16(a[mt], b[nt], acc[mt][nt], 0, 0, 0);
}

#define ACC_INIT(acc)                              \
  _Pragma("unroll") for (int i_ = 0; i_ < 4; ++i_) \
  _Pragma("unroll") for (int j_ = 0; j_ < 4; ++j_) \
      acc[i_][j_] = (v4f){0.f, 0.f, 0.f, 0.f};

// ---------------------------------------------------------------------------
// Input dtype detection: bf16 unit-normal shorts never have exponent >= 0xC0;
// fp32 data read as shorts has random-exponent low halves (~25% hits).
__global__ __launch_bounds__(256) void k_detect(const unsigned short* __restrict__ xs,
                                                int* __restrict__ flag) {
  __shared__ int cnt;
  if (threadIdx.x == 0) cnt = 0;
  __syncthreads();
  int local = 0;
  for (int i = threadIdx.x; i < 4096; i += 256) {
    const unsigned e = (xs[i] >> 7) & 0xFFu;
    if (e >= 0xC0u) ++local;
  }
  if (local) atomicAdd(&cnt, local);
  __syncthreads();
  if (threadIdx.x == 0) *flag = (cnt > 8) ? 1 : 0;
}

// Convert input (fp32 or bf16 per flag) to bf16 shorts.
__global__ __launch_bounds__(256) void k_convert(const void* __restrict__ in,
                                                 short* __restrict__ out, int n,
                                                 const int* __restrict__ flag) {
  const int stride = gridDim.x * blockDim.x;
  int i = blockIdx.x * blockDim.x + threadIdx.x;
  if (*flag != 0) {
    const float* p = (const float*)in;
    for (; i < n; i += stride) out[i] = f2bf(p[i]);
  } else {
    const short* p = (const short*)in;
    for (; i < n; i += stride) out[i] = p[i];
  }
}

// Convert input (fp32 or bf16 per flag) to fp32.
__global__ __launch_bounds__(256) void k_to_f32(const void* __restrict__ in,
                                                float* __restrict__ out, int n,
                                                const int* __restrict__ flag) {
  const int stride = gridDim.x * blockDim.x;
  int i = blockIdx.x * blockDim.x + threadIdx.x;
  if (*flag != 0) {
    const float* p = (const float*)in;
    for (; i < n; i += stride) out[i] = p[i];
  } else {
    const short* p = (const short*)in;
    for (; i < n; i += stride) out[i] = bf2f(p[i]);
  }
}

// ---------------------------------------------------------------------------
// Fused convert + transpose: in [R][C] (fp32 or bf16 per flag) -> out bf16 [C][R]
__global__ __launch_bounds__(256) void k_convT(const void* __restrict__ in,
                                               short* __restrict__ out, int R, int C,
                                               const int* __restrict__ flag) {
  __shared__ short t[32][33];
  const int xx = threadIdx.x & 31, y0 = threadIdx.x >> 5;
  const int c0 = blockIdx.x * 32, r0 = blockIdx.y * 32;
  if (*flag != 0) {
    const float* p = (const float*)in;
#pragma unroll
    for (int i = 0; i < 4; ++i) {
      int r = y0 + i * 8;
      t[r][xx] = f2bf(p[(size_t)(r0 + r) * C + c0 + xx]);
    }
  } else {
    const short* p = (const short*)in;
#pragma unroll
    for (int i = 0; i < 4; ++i) {
      int r = y0 + i * 8;
      t[r][xx] = p[(size_t)(r0 + r) * C + c0 + xx];
    }
  }
  __syncthreads();
#pragma unroll
  for (int i = 0; i < 4; ++i) {
    int r = y0 + i * 8;
    out[(size_t)(c0 + r) * R + r0 + xx] = t[xx][r];
  }
}

// ---------------------------------------------------------------------------
// GEMM1: qkv = x[8192][1024] @ Wqkv -> q,k into qk[8192][2048]; v written as vT[1024][8192]
__global__ __launch_bounds__(256) void k_gemm_qkv(const short* __restrict__ x,
                                                  const short* __restrict__ wt,  // [3072][1024]
                                                  short* __restrict__ qk,
                                                  short* __restrict__ vT) {
  __shared__ short As[4096], Bs[4096];
  const int tid = threadIdx.x, lane = tid & 63, wave = tid >> 6;
  const int wm = wave >> 1, wn = wave & 1;
  const int m0 = blockIdx.x * 128, n0 = blockIdx.y * 128;
  v4f acc[4][4];
  ACC_INIT(acc)
  for (int k0 = 0; k0 < 1024; k0 += 32) {
    __syncthreads();
    stage_tile(x + (size_t)m0 * 1024 + k0, 1024, As, tid);
    stage_tile(wt + (size_t)n0 * 1024 + k0, 1024, Bs, tid);
    __syncthreads();
    mma_step(As, Bs, acc, lane, wm, wn);
  }
  const int qd = lane >> 4, c16 = lane & 15;
#pragma unroll
  for (int mt = 0; mt < 4; ++mt) {
    const int rl = wm * 64 + mt * 16 + qd * 4;
#pragma unroll
    for (int nt = 0; nt < 4; ++nt) {
      const int cl = wn * 64 + nt * 16 + c16;
      const int n = n0 + cl;
      if (n < 2048) {  // q,k : row-major store
#pragma unroll
        for (int r = 0; r < 4; ++r)
          qk[(size_t)(m0 + rl + r) * 2048 + n] = f2bf(acc[mt][nt][r]);
      } else {  // v : transposed store, 4 consecutive tokens -> one 8B store
        S4 p;
        p.x = f2bf(acc[mt][nt][0]);
        p.y = f2bf(acc[mt][nt][1]);
        p.z = f2bf(acc[mt][nt][2]);
        p.w = f2bf(acc[mt][nt][3]);
        *reinterpret_cast<S4*>(vT + (size_t)(n - 2048) * 8192 + (m0 + rl)) = p;
      }
    }
  }
}

// ---------------------------------------------------------------------------
// QK^T + exp: causal tile (I,J), J<=I; E packed lower-triangular, tile idx I*(I+1)/2+J
__global__ __launch_bounds__(256) void k_qk_exp(const short* __restrict__ qk,
                                                short* __restrict__ E) {
  __shared__ short As[4096], Bs[4096];
  const int tid = threadIdx.x, lane = tid & 63, wave = tid >> 6;
  const int wm = wave >> 1, wn = wave & 1;
  const int b = (int)blockIdx.x;
  int I = (int)((sqrtf(8.f * (float)b + 1.f) - 1.f) * 0.5f);
  while ((I + 1) * (I + 2) / 2 <= b) ++I;
  while (I * (I + 1) / 2 > b) --I;
  const int J = b - I * (I + 1) / 2;
  const int m0 = I * 128, n0 = J * 128;
  v4f acc[4][4];
  ACC_INIT(acc)
  for (int k0 = 0; k0 < 1024; k0 += 32) {
    __syncthreads();
    stage_tile(qk + (size_t)m0 * 2048 + k0, 2048, As, tid);          // q rows
    stage_tile(qk + 1024 + (size_t)n0 * 2048 + k0, 2048, Bs, tid);   // k rows (B^T)
    __syncthreads();
    mma_step(As, Bs, acc, lane, wm, wn);
  }
  short* tb = E + (size_t)(I * (I + 1) / 2 + J) * 16384;
  const int qd = lane >> 4, c16 = lane & 15;
#pragma unroll
  for (int mt = 0; mt < 4; ++mt) {
    const int rl = wm * 64 + mt * 16 + qd * 4;
#pragma unroll
    for (int nt = 0; nt < 4; ++nt) {
      const int cl = wn * 64 + nt * 16 + c16;
      const int gj = n0 + cl;
#pragma unroll
      for (int r = 0; r < 4; ++r) {
        const int gi = m0 + rl + r;
        const float s = fminf(acc[mt][nt][r] * 0.03125f, 60.f);  // NaN-proof: cap exp arg
        const float e = (gj > gi) ? 0.f : __expf(s);
        tb[(rl + r) * 128 + cl] = f2bf(e);
      }
    }
  }
}

// ---------------------------------------------------------------------------
// PV: attn_out = (E @ v) / rowsum(E).  Row sums via ones-MFMA (land on same lanes/regs as C rows).
__global__ __launch_bounds__(256) void k_pv(const short* __restrict__ E,
                                            const short* __restrict__ vT,  // [1024][8192]
                                            short* __restrict__ attn) {
  __shared__ short As[4096], Bs[4096];
  const int tid = threadIdx.x, lane = tid & 63, wave = tid >> 6;
  const int wm = wave >> 1, wn = wave & 1;
  const int I = 63 - (int)blockIdx.x;  // heaviest tile-rows dispatched first
  const int n0 = (int)blockIdx.y * 128;
  const int m0 = I * 128;
  v4f acc[4][4];
  ACC_INIT(acc)
  v4f lacc[4];
#pragma unroll
  for (int i = 0; i < 4; ++i) lacc[i] = (v4f){0.f, 0.f, 0.f, 0.f};
  const v8bf ones = {(__bf16)1.f, (__bf16)1.f, (__bf16)1.f, (__bf16)1.f,
                     (__bf16)1.f, (__bf16)1.f, (__bf16)1.f, (__bf16)1.f};
  const size_t rowbase = (size_t)(I * (I + 1) / 2) * 16384;
  const int nch = (I + 1) * 4;
  for (int t = 0; t < nch; ++t) {
    const int J = t >> 2, jj = t & 3;
    const short* tb = E + rowbase + (size_t)J * 16384;
    __syncthreads();
    stage_tile(tb + jj * 32, 128, As, tid);
    stage_tile(vT + (size_t)n0 * 8192 + J * 128 + jj * 32, 8192, Bs, tid);
    __syncthreads();
    mma_step_pv(As, Bs, acc, lacc, ones, lane, wm, wn);
  }
  const int qd = lane >> 4, c16 = lane & 15;
#pragma unroll
  for (int mt = 0; mt < 4; ++mt) {
    const int rl = wm * 64 + mt * 16 + qd * 4;
#pragma unroll
    for (int nt = 0; nt < 4; ++nt) {
      const int cl = wn * 64 + nt * 16 + c16;
#pragma unroll
      for (int r = 0; r < 4; ++r) {
        const float o = acc[mt][nt][r] / fmaxf(lacc[mt][r], 1e-30f);  // NaN-proof divide
        attn[(size_t)(m0 + rl + r) * 1024 + n0 + cl] = f2bf(o);
      }
    }
  }
}

// ---------------------------------------------------------------------------
// GEMM2: out = attn[8192][1024] @ Wout + bout  -- FLOAT32 output
__global__ __launch_bounds__(256) void k_gemm_out(const short* __restrict__ attn,
                                                  const short* __restrict__ wt,  // [1024][1024] = Wout^T
                                                  const float* __restrict__ bout,
                                                  float* __restrict__ out) {
  __shared__ short As[4096], Bs[4096];
  const int tid = threadIdx.x, lane = tid & 63, wave = tid >> 6;
  const int wm = wave >> 1, wn = wave & 1;
  const int m0 = blockIdx.x * 128, n0 = blockIdx.y * 128;
  v4f acc[4][4];
  ACC_INIT(acc)
  for (int k0 = 0; k0 < 1024; k0 += 32) {
    __syncthreads();
    stage_tile(attn + (size_t)m0 * 1024 + k0, 1024, As, tid);
    stage_tile(wt + (size_t)n0 * 1024 + k0, 1024, Bs, tid);
    __syncthreads();
    mma_step(As, Bs, acc, lane, wm, wn);
  }
  const int qd = lane >> 4, c16 = lane & 15;
#pragma unroll
  for (int mt = 0; mt < 4; ++mt) {
    const int rl = wm * 64 + mt * 16 + qd * 4;
#pragma unroll
    for (int nt = 0; nt < 4; ++nt) {
      const int cl = wn * 64 + nt * 16 + c16;
      const float bias = bout[n0 + cl];
#pragma unroll
      for (int r = 0; r < 4; ++r)
        out[(size_t)(m0 + rl + r) * 1024 + n0 + cl] = acc[mt][nt][r] + bias;
    }
  }
}

// ---------------------------------------------------------------------------
extern "C" void kernel_launch(void* const* d_in, const int* in_sizes, int n_in,
                              void* d_out, int out_size, void* d_ws, size_t ws_size,
                              hipStream_t stream) {
  (void)out_size; (void)ws_size;
  // Select inputs by element count (robust to ordering): x=8.4M, Wqkv=3.1M,
  // Wout=1.05M, bout=1K.
  const void *x = d_in[0], *Wqkv = d_in[1], *Wout = d_in[2], *bout = d_in[3];
  for (int i = 0; i < n_in; ++i) {
    switch (in_sizes[i]) {
      case 8192 * 1024: x = d_in[i]; break;
      case 1024 * 3072: Wqkv = d_in[i]; break;
      case 1024 * 1024: Wout = d_in[i]; break;
      case 1024:        bout = d_in[i]; break;
      default: break;
    }
  }

  char* ws = (char*)d_ws;
  short* qk    = (short*)(ws);                // 8192x2048 bf16 (q | k)   33.55 MB
  short* vT    = (short*)(ws + 33554432);     // 1024x8192 bf16           16.78 MB
  short* E     = (short*)(ws + 50331648);     // 2080 tiles of 128x128    68.16 MB  (ends 118,489,088)
  short* xb    = (short*)(ws + 118489088);    // 8192x1024 bf16           16.78 MB  (attn aliases xb)
  short* attn  = xb;                          //   xb dead after GEMM1; attn written by k_pv
  short* WqT   = (short*)(ws + 135266304);    // 3072x1024 bf16            6.29 MB
  short* WoT   = (short*)(ws + 141557760);    // 1024x1024 bf16            2.10 MB
  float* boutf = (float*)(ws + 143654912);    // 1024 fp32                 4 KB
  int*   flag  = (int*)  (ws + 143659008);    // dtype flag   total ~143.66 MB

  k_detect<<<1, 256, 0, stream>>>((const unsigned short*)x, flag);
  k_convert<<<1024, 256, 0, stream>>>(x, xb, 8192 * 1024, flag);
  k_to_f32<<<1, 256, 0, stream>>>(bout, boutf, 1024, flag);
  k_convT<<<dim3(96, 32), 256, 0, stream>>>(Wqkv, WqT, 1024, 3072, flag);
  k_convT<<<dim3(32, 32), 256, 0, stream>>>(Wout, WoT, 1024, 1024, flag);
  k_gemm_qkv<<<dim3(64, 24), 256, 0, stream>>>(xb, WqT, qk, vT);
  k_qk_exp<<<dim3(2080), 256, 0, stream>>>(qk, E);
  k_pv<<<dim3(64, 8), 256, 0, stream>>>(E, vT, attn);
  k_gemm_out<<<dim3(64, 8), 256, 0, stream>>>(attn, WoT, boutf, (float*)d_out);
}

// Round 6
// 485.322 us; speedup vs baseline: 1.0485x; 1.0485x over previous
//
#include <hip/hip_runtime.h>
#include <hip/hip_bf16.h>

// ---------------------------------------------------------------------------
// Attention block, N=8192 D=1024 (inputs fp32 or bf16, runtime-detected;
// output float32):
//   qkv = x @ Wqkv ; S = q k^T / 32 (causal) ; P = softmax(S) ; O = P v
//   out = O @ Wout + bout
// Softmax without max-subtraction (S ~ N(0,1)); exp arg clamped, divide
// guarded (NaN-proof). E = exp(S) packed lower-triangular bf16.
// R6: softmax denominators l[8192] computed in k_qk_exp's epilogue
// (shfl reduce + atomicAdd) instead of ones-MFMA in PV; k_pv retiled to
// 128x64 with two tile-rows per block (I=bx and 63-bx) -> all 512 blocks do
// exactly 260 chunk-iters (perfect balance; was 16% MfmaUtil from imbalance).
// ---------------------------------------------------------------------------

typedef __bf16 v8bf __attribute__((ext_vector_type(8)));
typedef float  v4f  __attribute__((ext_vector_type(4)));

struct __align__(8) S4 { short x, y, z, w; };

__device__ inline short f2bf(float f) {
  __hip_bfloat16 h = __float2bfloat16(f);
  return *reinterpret_cast<short*>(&h);
}
__device__ inline float bf2f(short s) {
  unsigned u = ((unsigned)(unsigned short)s) << 16;
  float f;
  __builtin_memcpy(&f, &u, 4);
  return f;
}

// Stage a 128x32 bf16 tile (row-major, leading dim ldg) into LDS [128][32].
__device__ inline void stage_tile(const short* gbase, int ldg, short* lds, int tid) {
#pragma unroll
  for (int p = 0; p < 2; ++p) {
    const int c = p * 256 + tid;
    const v8bf val = *(const v8bf*)(gbase + (size_t)(c >> 2) * ldg + (c & 3) * 8);
    *(v8bf*)(lds + c * 8) = val;
  }
}

// One BK=32 step for 128x128 tiles: 8 ds_read_b128 + 16 MFMA.
__device__ inline void mma_step(const short* As, const short* Bs, v4f acc[4][4],
                                int lane, int wm, int wn) {
  const int qd = lane >> 4, r16 = lane & 15;
  const short* ab = As + (wm * 64 + r16) * 32 + qd * 8;
  const short* bb = Bs + (wn * 64 + r16) * 32 + qd * 8;
  v8bf a[4], b[4];
#pragma unroll
  for (int t = 0; t < 4; ++t) {
    a[t] = *(const v8bf*)(ab + t * 512);
    b[t] = *(const v8bf*)(bb + t * 512);
  }
#pragma unroll
  for (int mt = 0; mt < 4; ++mt)
#pragma unroll
    for (int nt = 0; nt < 4; ++nt)
      acc[mt][nt] = __builtin_amdgcn_mfma_f32_16x16x32_bf16(a[mt], b[nt], acc[mt][nt], 0, 0, 0);
}

#define ACC_INIT(acc)                              \
  _Pragma("unroll") for (int i_ = 0; i_ < 4; ++i_) \
  _Pragma("unroll") for (int j_ = 0; j_ < 4; ++j_) \
      acc[i_][j_] = (v4f){0.f, 0.f, 0.f, 0.f};

// ---------------------------------------------------------------------------
__global__ __launch_bounds__(256) void k_zerof(float* __restrict__ p, int n) {
  const int i = blockIdx.x * 256 + threadIdx.x;
  if (i < n) p[i] = 0.f;
}

// Input dtype detection: bf16 unit-normal shorts never have exponent >= 0xC0.
__global__ __launch_bounds__(256) void k_detect(const unsigned short* __restrict__ xs,
                                                int* __restrict__ flag) {
  __shared__ int cnt;
  if (threadIdx.x == 0) cnt = 0;
  __syncthreads();
  int local = 0;
  for (int i = threadIdx.x; i < 4096; i += 256) {
    const unsigned e = (xs[i] >> 7) & 0xFFu;
    if (e >= 0xC0u) ++local;
  }
  if (local) atomicAdd(&cnt, local);
  __syncthreads();
  if (threadIdx.x == 0) *flag = (cnt > 8) ? 1 : 0;
}

// Convert input (fp32 or bf16 per flag) to bf16 shorts.
__global__ __launch_bounds__(256) void k_convert(const void* __restrict__ in,
                                                 short* __restrict__ out, int n,
                                                 const int* __restrict__ flag) {
  const int stride = gridDim.x * blockDim.x;
  int i = blockIdx.x * blockDim.x + threadIdx.x;
  if (*flag != 0) {
    const float* p = (const float*)in;
    for (; i < n; i += stride) out[i] = f2bf(p[i]);
  } else {
    const short* p = (const short*)in;
    for (; i < n; i += stride) out[i] = p[i];
  }
}

// Convert input (fp32 or bf16 per flag) to fp32.
__global__ __launch_bounds__(256) void k_to_f32(const void* __restrict__ in,
                                                float* __restrict__ out, int n,
                                                const int* __restrict__ flag) {
  const int stride = gridDim.x * blockDim.x;
  int i = blockIdx.x * blockDim.x + threadIdx.x;
  if (*flag != 0) {
    const float* p = (const float*)in;
    for (; i < n; i += stride) out[i] = p[i];
  } else {
    const short* p = (const short*)in;
    for (; i < n; i += stride) out[i] = bf2f(p[i]);
  }
}

// ---------------------------------------------------------------------------
// Fused convert + transpose: in [R][C] (fp32 or bf16 per flag) -> out bf16 [C][R]
__global__ __launch_bounds__(256) void k_convT(const void* __restrict__ in,
                                               short* __restrict__ out, int R, int C,
                                               const int* __restrict__ flag) {
  __shared__ short t[32][33];
  const int xx = threadIdx.x & 31, y0 = threadIdx.x >> 5;
  const int c0 = blockIdx.x * 32, r0 = blockIdx.y * 32;
  if (*flag != 0) {
    const float* p = (const float*)in;
#pragma unroll
    for (int i = 0; i < 4; ++i) {
      int r = y0 + i * 8;
      t[r][xx] = f2bf(p[(size_t)(r0 + r) * C + c0 + xx]);
    }
  } else {
    const short* p = (const short*)in;
#pragma unroll
    for (int i = 0; i < 4; ++i) {
      int r = y0 + i * 8;
      t[r][xx] = p[(size_t)(r0 + r) * C + c0 + xx];
    }
  }
  __syncthreads();
#pragma unroll
  for (int i = 0; i < 4; ++i) {
    int r = y0 + i * 8;
    out[(size_t)(c0 + r) * R + r0 + xx] = t[xx][r];
  }
}

// ---------------------------------------------------------------------------
// GEMM1: qkv = x[8192][1024] @ Wqkv -> q,k into qk[8192][2048]; v written as vT[1024][8192]
__global__ __launch_bounds__(256) void k_gemm_qkv(const short* __restrict__ x,
                                                  const short* __restrict__ wt,  // [3072][1024]
                                                  short* __restrict__ qk,
                                                  short* __restrict__ vT) {
  __shared__ short As[4096], Bs[4096];
  const int tid = threadIdx.x, lane = tid & 63, wave = tid >> 6;
  const int wm = wave >> 1, wn = wave & 1;
  const int m0 = blockIdx.x * 128, n0 = blockIdx.y * 128;
  v4f acc[4][4];
  ACC_INIT(acc)
  for (int k0 = 0; k0 < 1024; k0 += 32) {
    __syncthreads();
    stage_tile(x + (size_t)m0 * 1024 + k0, 1024, As, tid);
    stage_tile(wt + (size_t)n0 * 1024 + k0, 1024, Bs, tid);
    __syncthreads();
    mma_step(As, Bs, acc, lane, wm, wn);
  }
  const int qd = lane >> 4, c16 = lane & 15;
#pragma unroll
  for (int mt = 0; mt < 4; ++mt) {
    const int rl = wm * 64 + mt * 16 + qd * 4;
#pragma unroll
    for (int nt = 0; nt < 4; ++nt) {
      const int cl = wn * 64 + nt * 16 + c16;
      const int n = n0 + cl;
      if (n < 2048) {  // q,k : row-major store
#pragma unroll
        for (int r = 0; r < 4; ++r)
          qk[(size_t)(m0 + rl + r) * 2048 + n] = f2bf(acc[mt][nt][r]);
      } else {  // v : transposed store, 4 consecutive tokens -> one 8B store
        S4 p;
        p.x = f2bf(acc[mt][nt][0]);
        p.y = f2bf(acc[mt][nt][1]);
        p.z = f2bf(acc[mt][nt][2]);
        p.w = f2bf(acc[mt][nt][3]);
        *reinterpret_cast<S4*>(vT + (size_t)(n - 2048) * 8192 + (m0 + rl)) = p;
      }
    }
  }
}

// ---------------------------------------------------------------------------
// QK^T + exp: causal tile (I,J), J<=I; E packed lower-triangular.
// Epilogue also accumulates per-row sums of exp into l[8192] via atomicAdd.
__global__ __launch_bounds__(256) void k_qk_exp(const short* __restrict__ qk,
                                                short* __restrict__ E,
                                                float* __restrict__ l) {
  __shared__ short As[4096], Bs[4096];
  __shared__ float srow[128][2];
  const int tid = threadIdx.x, lane = tid & 63, wave = tid >> 6;
  const int wm = wave >> 1, wn = wave & 1;
  const int b = (int)blockIdx.x;
  int I = (int)((sqrtf(8.f * (float)b + 1.f) - 1.f) * 0.5f);
  while ((I + 1) * (I + 2) / 2 <= b) ++I;
  while (I * (I + 1) / 2 > b) --I;
  const int J = b - I * (I + 1) / 2;
  const int m0 = I * 128, n0 = J * 128;
  v4f acc[4][4];
  ACC_INIT(acc)
  for (int k0 = 0; k0 < 1024; k0 += 32) {
    __syncthreads();
    stage_tile(qk + (size_t)m0 * 2048 + k0, 2048, As, tid);          // q rows
    stage_tile(qk + 1024 + (size_t)n0 * 2048 + k0, 2048, Bs, tid);   // k rows (B^T)
    __syncthreads();
    mma_step(As, Bs, acc, lane, wm, wn);
  }
  short* tb = E + (size_t)(I * (I + 1) / 2 + J) * 16384;
  const int qd = lane >> 4, c16 = lane & 15;
  float rp[4][4];
#pragma unroll
  for (int mt = 0; mt < 4; ++mt)
#pragma unroll
    for (int r = 0; r < 4; ++r) rp[mt][r] = 0.f;
#pragma unroll
  for (int mt = 0; mt < 4; ++mt) {
    const int rl = wm * 64 + mt * 16 + qd * 4;
#pragma unroll
    for (int nt = 0; nt < 4; ++nt) {
      const int cl = wn * 64 + nt * 16 + c16;
      const int gj = n0 + cl;
#pragma unroll
      for (int r = 0; r < 4; ++r) {
        const int gi = m0 + rl + r;
        const float s = fminf(acc[mt][nt][r] * 0.03125f, 60.f);  // NaN-proof
        const float e = (gj > gi) ? 0.f : __expf(s);
        tb[(rl + r) * 128 + cl] = f2bf(e);
        rp[mt][r] += e;
      }
    }
  }
  // row-sum: butterfly over the 16-lane column group, combine wn waves in LDS.
#pragma unroll
  for (int mt = 0; mt < 4; ++mt)
#pragma unroll
    for (int r = 0; r < 4; ++r) {
      float v = rp[mt][r];
      v += __shfl_xor(v, 1);
      v += __shfl_xor(v, 2);
      v += __shfl_xor(v, 4);
      v += __shfl_xor(v, 8);
      rp[mt][r] = v;
    }
  if ((lane & 15) == 0) {
#pragma unroll
    for (int mt = 0; mt < 4; ++mt)
#pragma unroll
      for (int r = 0; r < 4; ++r)
        srow[wm * 64 + mt * 16 + qd * 4 + r][wn] = rp[mt][r];
  }
  __syncthreads();
  if (tid < 128) atomicAdd(&l[m0 + tid], srow[tid][0] + srow[tid][1]);
}

// ---------------------------------------------------------------------------
// PV: attn = (E @ v) / l.  Tile 128x64; each block does tile-rows I=bx and
// I=63-bx (exactly 260 chunk-iters per block -> perfect balance).
__global__ __launch_bounds__(256) void k_pv(const short* __restrict__ E,
                                            const short* __restrict__ vT,  // [1024][8192]
                                            const float* __restrict__ l,
                                            short* __restrict__ attn) {
  __shared__ short As[4096], Bs[2048];
  const int tid = threadIdx.x, lane = tid & 63, wave = tid >> 6;
  const int wm = wave >> 1, wn = wave & 1;
  const int bx = (int)blockIdx.x;       // 0..31
  const int n0 = (int)blockIdx.y * 64;  // 0..15 -> cols
  const int qd = lane >> 4, r16 = lane & 15;
  for (int half = 0; half < 2; ++half) {
    const int I = half ? 63 - bx : bx;
    const int m0 = I * 128;
    const size_t rowbase = (size_t)(I * (I + 1) / 2) * 16384;
    v4f acc[4][2];
#pragma unroll
    for (int mt = 0; mt < 4; ++mt)
#pragma unroll
      for (int nt = 0; nt < 2; ++nt) acc[mt][nt] = (v4f){0.f, 0.f, 0.f, 0.f};
    const int nch = (I + 1) * 4;
    for (int t = 0; t < nch; ++t) {
      const int J = t >> 2, jj = t & 3;
      __syncthreads();
      stage_tile(E + rowbase + (size_t)J * 16384 + jj * 32, 128, As, tid);
      {  // B: vT rows n0..n0+64, k-cols J*128+jj*32..+32  (64x32 = one pass)
        const short* g = vT + (size_t)(n0 + (tid >> 2)) * 8192 + (size_t)J * 128 + jj * 32 + (tid & 3) * 8;
        *(v8bf*)(Bs + tid * 8) = *(const v8bf*)g;
      }
      __syncthreads();
      const short* ab = As + (wm * 64 + r16) * 32 + qd * 8;
      const short* bb = Bs + (wn * 32 + r16) * 32 + qd * 8;
      v8bf a[4], b[2];
#pragma unroll
      for (int u = 0; u < 4; ++u) a[u] = *(const v8bf*)(ab + u * 512);
#pragma unroll
      for (int u = 0; u < 2; ++u) b[u] = *(const v8bf*)(bb + u * 512);
#pragma unroll
      for (int mt = 0; mt < 4; ++mt)
#pragma unroll
        for (int nt = 0; nt < 2; ++nt)
          acc[mt][nt] = __builtin_amdgcn_mfma_f32_16x16x32_bf16(a[mt], b[nt], acc[mt][nt], 0, 0, 0);
    }
    const int c16 = lane & 15;
#pragma unroll
    for (int mt = 0; mt < 4; ++mt) {
      const int rl = wm * 64 + mt * 16 + qd * 4;
      float inv[4];
#pragma unroll
      for (int r = 0; r < 4; ++r) inv[r] = 1.0f / fmaxf(l[m0 + rl + r], 1e-30f);
#pragma unroll
      for (int nt = 0; nt < 2; ++nt) {
        const int cl = wn * 32 + nt * 16 + c16;
#pragma unroll
        for (int r = 0; r < 4; ++r)
          attn[(size_t)(m0 + rl + r) * 1024 + n0 + cl] = f2bf(acc[mt][nt][r] * inv[r]);
      }
    }
    __syncthreads();  // acc consumed; safe to restage LDS next half
  }
}

// ---------------------------------------------------------------------------
// GEMM2: out = attn[8192][1024] @ Wout + bout  -- FLOAT32 output
__global__ __launch_bounds__(256) void k_gemm_out(const short* __restrict__ attn,
                                                  const short* __restrict__ wt,  // [1024][1024] = Wout^T
                                                  const float* __restrict__ bout,
                                                  float* __restrict__ out) {
  __shared__ short As[4096], Bs[4096];
  const int tid = threadIdx.x, lane = tid & 63, wave = tid >> 6;
  const int wm = wave >> 1, wn = wave & 1;
  const int m0 = blockIdx.x * 128, n0 = blockIdx.y * 128;
  v4f acc[4][4];
  ACC_INIT(acc)
  for (int k0 = 0; k0 < 1024; k0 += 32) {
    __syncthreads();
    stage_tile(attn + (size_t)m0 * 1024 + k0, 1024, As, tid);
    stage_tile(wt + (size_t)n0 * 1024 + k0, 1024, Bs, tid);
    __syncthreads();
    mma_step(As, Bs, acc, lane, wm, wn);
  }
  const int qd = lane >> 4, c16 = lane & 15;
#pragma unroll
  for (int mt = 0; mt < 4; ++mt) {
    const int rl = wm * 64 + mt * 16 + qd * 4;
#pragma unroll
    for (int nt = 0; nt < 4; ++nt) {
      const int cl = wn * 64 + nt * 16 + c16;
      const float bias = bout[n0 + cl];
#pragma unroll
      for (int r = 0; r < 4; ++r)
        out[(size_t)(m0 + rl + r) * 1024 + n0 + cl] = acc[mt][nt][r] + bias;
    }
  }
}

// ---------------------------------------------------------------------------
extern "C" void kernel_launch(void* const* d_in, const int* in_sizes, int n_in,
                              void* d_out, int out_size, void* d_ws, size_t ws_size,
                              hipStream_t stream) {
  (void)out_size; (void)ws_size;
  const void *x = d_in[0], *Wqkv = d_in[1], *Wout = d_in[2], *bout = d_in[3];
  for (int i = 0; i < n_in; ++i) {
    switch (in_sizes[i]) {
      case 8192 * 1024: x = d_in[i]; break;
      case 1024 * 3072: Wqkv = d_in[i]; break;
      case 1024 * 1024: Wout = d_in[i]; break;
      case 1024:        bout = d_in[i]; break;
      default: break;
    }
  }

  char* ws = (char*)d_ws;
  short* qk    = (short*)(ws);                // 8192x2048 bf16 (q | k)   33.55 MB
  short* vT    = (short*)(ws + 33554432);     // 1024x8192 bf16           16.78 MB
  short* E     = (short*)(ws + 50331648);     // 2080 tiles of 128x128    68.16 MB
  short* xb    = (short*)(ws + 118489088);    // 8192x1024 bf16           16.78 MB
  short* attn  = xb;                          //   xb dead after GEMM1
  short* WqT   = (short*)(ws + 135266304);    // 3072x1024 bf16            6.29 MB
  short* WoT   = (short*)(ws + 141557760);    // 1024x1024 bf16            2.10 MB
  float* boutf = (float*)(ws + 143654912);    // 1024 fp32
  float* lsum  = (float*)(ws + 143659008);    // 8192 fp32 softmax denominators
  int*   flag  = (int*)  (ws + 143691776);    // dtype flag

  k_detect<<<1, 256, 0, stream>>>((const unsigned short*)x, flag);
  k_zerof<<<32, 256, 0, stream>>>(lsum, 8192);
  k_convert<<<1024, 256, 0, stream>>>(x, xb, 8192 * 1024, flag);
  k_to_f32<<<1, 256, 0, stream>>>(bout, boutf, 1024, flag);
  k_convT<<<dim3(96, 32), 256, 0, stream>>>(Wqkv, WqT, 1024, 3072, flag);
  k_convT<<<dim3(32, 32), 256, 0, stream>>>(Wout, WoT, 1024, 1024, flag);
  k_gemm_qkv<<<dim3(64, 24), 256, 0, stream>>>(xb, WqT, qk, vT);
  k_qk_exp<<<dim3(2080), 256, 0, stream>>>(qk, E, lsum);
  k_pv<<<dim3(32, 16), 256, 0, stream>>>(E, vT, lsum, attn);
  k_gemm_out<<<dim3(64, 8), 256, 0, stream>>>(attn, WoT, boutf, (float*)d_out);
}

// Round 7
// 412.592 us; speedup vs baseline: 1.2333x; 1.1763x over previous
//
#include <hip/hip_runtime.h>
#include <hip/hip_bf16.h>

// ---------------------------------------------------------------------------
// Attention block, N=8192 D=1024 (inputs fp32 or bf16, runtime-detected;
// output float32):
//   qkv = x @ Wqkv ; S = q k^T / 32 (causal) ; P = softmax(S) ; O = P v
//   out = O @ Wout + bout
// R7: (a) k_pv restructured: full 128x128 J-tile staged per barrier pair
// (48 KB LDS) + register double-buffer prefetch of tile J+1 overlapping the
// 32-MFMA compute of tile J (was global-latency-bound at 1660 cyc/iter,
// MfmaUtil 16%). (b) GEMM kernels back on global_load_lds width-16 staging
// (m97 path; exonerated — the r1-4 bug was output dtype).
// ---------------------------------------------------------------------------

typedef __bf16 v8bf __attribute__((ext_vector_type(8)));
typedef float  v4f  __attribute__((ext_vector_type(4)));

struct __align__(8) S4 { short x, y, z, w; };

__device__ inline short f2bf(float f) {
  __hip_bfloat16 h = __float2bfloat16(f);
  return *reinterpret_cast<short*>(&h);
}
__device__ inline float bf2f(short s) {
  unsigned u = ((unsigned)(unsigned short)s) << 16;
  float f;
  __builtin_memcpy(&f, &u, 4);
  return f;
}

// Async stage of a 128x32 bf16 tile (row-major, ldg) into LDS [128][32].
// global_load_lds width=16: LDS dest is wave-uniform base + lane*16B.
__device__ inline void stage_tile(const short* gbase, int ldg, short* lds, int tid) {
#pragma unroll
  for (int p = 0; p < 2; ++p) {
    const int c = p * 256 + tid;                    // 16B-chunk id; lane order matches dest
    const short* g = gbase + (size_t)(c >> 2) * ldg + (c & 3) * 8;
    short* l = lds + p * 2048 + (tid >> 6) * 512;   // wave-uniform; HW adds lane*16B
    __builtin_amdgcn_global_load_lds(
        (__attribute__((address_space(1))) void*)(void*)g,
        (__attribute__((address_space(3))) void*)l, 16, 0, 0);
  }
}

// One BK=32 step for 128x128 tiles: 8 ds_read_b128 + 16 MFMA.
__device__ inline void mma_step(const short* As, const short* Bs, v4f acc[4][4],
                                int lane, int wm, int wn) {
  const int qd = lane >> 4, r16 = lane & 15;
  const short* ab = As + (wm * 64 + r16) * 32 + qd * 8;
  const short* bb = Bs + (wn * 64 + r16) * 32 + qd * 8;
  v8bf a[4], b[4];
#pragma unroll
  for (int t = 0; t < 4; ++t) {
    a[t] = *(const v8bf*)(ab + t * 512);
    b[t] = *(const v8bf*)(bb + t * 512);
  }
#pragma unroll
  for (int mt = 0; mt < 4; ++mt)
#pragma unroll
    for (int nt = 0; nt < 4; ++nt)
      acc[mt][nt] = __builtin_amdgcn_mfma_f32_16x16x32_bf16(a[mt], b[nt], acc[mt][nt], 0, 0, 0);
}

#define ACC_INIT(acc)                              \
  _Pragma("unroll") for (int i_ = 0; i_ < 4; ++i_) \
  _Pragma("unroll") for (int j_ = 0; j_ < 4; ++j_) \
      acc[i_][j_] = (v4f){0.f, 0.f, 0.f, 0.f};

// ---------------------------------------------------------------------------
__global__ __launch_bounds__(256) void k_zerof(float* __restrict__ p, int n) {
  const int i = blockIdx.x * 256 + threadIdx.x;
  if (i < n) p[i] = 0.f;
}

// Input dtype detection: bf16 unit-normal shorts never have exponent >= 0xC0.
__global__ __launch_bounds__(256) void k_detect(const unsigned short* __restrict__ xs,
                                                int* __restrict__ flag) {
  __shared__ int cnt;
  if (threadIdx.x == 0) cnt = 0;
  __syncthreads();
  int local = 0;
  for (int i = threadIdx.x; i < 4096; i += 256) {
    const unsigned e = (xs[i] >> 7) & 0xFFu;
    if (e >= 0xC0u) ++local;
  }
  if (local) atomicAdd(&cnt, local);
  __syncthreads();
  if (threadIdx.x == 0) *flag = (cnt > 8) ? 1 : 0;
}

// Convert input (fp32 or bf16 per flag) to bf16 shorts.
__global__ __launch_bounds__(256) void k_convert(const void* __restrict__ in,
                                                 short* __restrict__ out, int n,
                                                 const int* __restrict__ flag) {
  const int stride = gridDim.x * blockDim.x;
  int i = blockIdx.x * blockDim.x + threadIdx.x;
  if (*flag != 0) {
    const float* p = (const float*)in;
    for (; i < n; i += stride) out[i] = f2bf(p[i]);
  } else {
    const short* p = (const short*)in;
    for (; i < n; i += stride) out[i] = p[i];
  }
}

// Convert input (fp32 or bf16 per flag) to fp32.
__global__ __launch_bounds__(256) void k_to_f32(const void* __restrict__ in,
                                                float* __restrict__ out, int n,
                                                const int* __restrict__ flag) {
  const int stride = gridDim.x * blockDim.x;
  int i = blockIdx.x * blockDim.x + threadIdx.x;
  if (*flag != 0) {
    const float* p = (const float*)in;
    for (; i < n; i += stride) out[i] = p[i];
  } else {
    const short* p = (const short*)in;
    for (; i < n; i += stride) out[i] = bf2f(p[i]);
  }
}

// ---------------------------------------------------------------------------
// Fused convert + transpose: in [R][C] (fp32 or bf16 per flag) -> out bf16 [C][R]
__global__ __launch_bounds__(256) void k_convT(const void* __restrict__ in,
                                               short* __restrict__ out, int R, int C,
                                               const int* __restrict__ flag) {
  __shared__ short t[32][33];
  const int xx = threadIdx.x & 31, y0 = threadIdx.x >> 5;
  const int c0 = blockIdx.x * 32, r0 = blockIdx.y * 32;
  if (*flag != 0) {
    const float* p = (const float*)in;
#pragma unroll
    for (int i = 0; i < 4; ++i) {
      int r = y0 + i * 8;
      t[r][xx] = f2bf(p[(size_t)(r0 + r) * C + c0 + xx]);
    }
  } else {
    const short* p = (const short*)in;
#pragma unroll
    for (int i = 0; i < 4; ++i) {
      int r = y0 + i * 8;
      t[r][xx] = p[(size_t)(r0 + r) * C + c0 + xx];
    }
  }
  __syncthreads();
#pragma unroll
  for (int i = 0; i < 4; ++i) {
    int r = y0 + i * 8;
    out[(size_t)(c0 + r) * R + r0 + xx] = t[xx][r];
  }
}

// ---------------------------------------------------------------------------
// GEMM1: qkv = x[8192][1024] @ Wqkv -> q,k into qk[8192][2048]; v written as vT[1024][8192]
__global__ __launch_bounds__(256) void k_gemm_qkv(const short* __restrict__ x,
                                                  const short* __restrict__ wt,  // [3072][1024]
                                                  short* __restrict__ qk,
                                                  short* __restrict__ vT) {
  __shared__ short As[4096], Bs[4096];
  const int tid = threadIdx.x, lane = tid & 63, wave = tid >> 6;
  const int wm = wave >> 1, wn = wave & 1;
  const int m0 = blockIdx.x * 128, n0 = blockIdx.y * 128;
  v4f acc[4][4];
  ACC_INIT(acc)
  for (int k0 = 0; k0 < 1024; k0 += 32) {
    __syncthreads();
    stage_tile(x + (size_t)m0 * 1024 + k0, 1024, As, tid);
    stage_tile(wt + (size_t)n0 * 1024 + k0, 1024, Bs, tid);
    __syncthreads();
    mma_step(As, Bs, acc, lane, wm, wn);
  }
  const int qd = lane >> 4, c16 = lane & 15;
#pragma unroll
  for (int mt = 0; mt < 4; ++mt) {
    const int rl = wm * 64 + mt * 16 + qd * 4;
#pragma unroll
    for (int nt = 0; nt < 4; ++nt) {
      const int cl = wn * 64 + nt * 16 + c16;
      const int n = n0 + cl;
      if (n < 2048) {  // q,k : row-major store
#pragma unroll
        for (int r = 0; r < 4; ++r)
          qk[(size_t)(m0 + rl + r) * 2048 + n] = f2bf(acc[mt][nt][r]);
      } else {  // v : transposed store, 4 consecutive tokens -> one 8B store
        S4 p;
        p.x = f2bf(acc[mt][nt][0]);
        p.y = f2bf(acc[mt][nt][1]);
        p.z = f2bf(acc[mt][nt][2]);
        p.w = f2bf(acc[mt][nt][3]);
        *reinterpret_cast<S4*>(vT + (size_t)(n - 2048) * 8192 + (m0 + rl)) = p;
      }
    }
  }
}

// ---------------------------------------------------------------------------
// QK^T + exp: causal tile (I,J), J<=I; E packed lower-triangular.
// Epilogue accumulates per-row sums of exp into l[8192] via atomicAdd.
__global__ __launch_bounds__(256) void k_qk_exp(const short* __restrict__ qk,
                                                short* __restrict__ E,
                                                float* __restrict__ l) {
  __shared__ short As[4096], Bs[4096];
  __shared__ float srow[128][2];
  const int tid = threadIdx.x, lane = tid & 63, wave = tid >> 6;
  const int wm = wave >> 1, wn = wave & 1;
  const int b = (int)blockIdx.x;
  int I = (int)((sqrtf(8.f * (float)b + 1.f) - 1.f) * 0.5f);
  while ((I + 1) * (I + 2) / 2 <= b) ++I;
  while (I * (I + 1) / 2 > b) --I;
  const int J = b - I * (I + 1) / 2;
  const int m0 = I * 128, n0 = J * 128;
  v4f acc[4][4];
  ACC_INIT(acc)
  for (int k0 = 0; k0 < 1024; k0 += 32) {
    __syncthreads();
    stage_tile(qk + (size_t)m0 * 2048 + k0, 2048, As, tid);          // q rows
    stage_tile(qk + 1024 + (size_t)n0 * 2048 + k0, 2048, Bs, tid);   // k rows (B^T)
    __syncthreads();
    mma_step(As, Bs, acc, lane, wm, wn);
  }
  short* tb = E + (size_t)(I * (I + 1) / 2 + J) * 16384;
  const int qd = lane >> 4, c16 = lane & 15;
  float rp[4][4];
#pragma unroll
  for (int mt = 0; mt < 4; ++mt)
#pragma unroll
    for (int r = 0; r < 4; ++r) rp[mt][r] = 0.f;
#pragma unroll
  for (int mt = 0; mt < 4; ++mt) {
    const int rl = wm * 64 + mt * 16 + qd * 4;
#pragma unroll
    for (int nt = 0; nt < 4; ++nt) {
      const int cl = wn * 64 + nt * 16 + c16;
      const int gj = n0 + cl;
#pragma unroll
      for (int r = 0; r < 4; ++r) {
        const int gi = m0 + rl + r;
        const float s = fminf(acc[mt][nt][r] * 0.03125f, 60.f);  // NaN-proof
        const float e = (gj > gi) ? 0.f : __expf(s);
        tb[(rl + r) * 128 + cl] = f2bf(e);
        rp[mt][r] += e;
      }
    }
  }
#pragma unroll
  for (int mt = 0; mt < 4; ++mt)
#pragma unroll
    for (int r = 0; r < 4; ++r) {
      float v = rp[mt][r];
      v += __shfl_xor(v, 1);
      v += __shfl_xor(v, 2);
      v += __shfl_xor(v, 4);
      v += __shfl_xor(v, 8);
      rp[mt][r] = v;
    }
  if ((lane & 15) == 0) {
#pragma unroll
    for (int mt = 0; mt < 4; ++mt)
#pragma unroll
      for (int r = 0; r < 4; ++r)
        srow[wm * 64 + mt * 16 + qd * 4 + r][wn] = rp[mt][r];
  }
  __syncthreads();
  if (tid < 128) atomicAdd(&l[m0 + tid], srow[tid][0] + srow[tid][1]);
}

// ---------------------------------------------------------------------------
// PV: attn = (E @ v) / l.  Tile 128x64; block does tile-rows I=bx and 63-bx
// (65 J-tiles each -> perfect balance). Full 128-wide J-tile staged per
// barrier pair (As 32KB + Bs 16KB); register double-buffer prefetches tile
// J+1's 192B/thread during tile J's 32 MFMAs (latency overlap).
__device__ inline void pv_load(const short* __restrict__ Et, const short* __restrict__ vb,
                               v8bf av[8], v8bf bv[4], int tid) {
#pragma unroll
  for (int p = 0; p < 8; ++p) {
    const int c = p * 256 + tid;                      // [128 rows][16 col-chunks]
    av[p] = *(const v8bf*)(Et + (c >> 4) * 128 + (c & 15) * 8);
  }
#pragma unroll
  for (int p = 0; p < 4; ++p) {
    const int c = p * 256 + tid;                      // [64 rows][16 col-chunks]
    bv[p] = *(const v8bf*)(vb + (size_t)(c >> 4) * 8192 + (c & 15) * 8);
  }
}
__device__ inline void pv_write(short* __restrict__ As, short* __restrict__ Bs,
                                const v8bf av[8], const v8bf bv[4], int tid) {
#pragma unroll
  for (int p = 0; p < 8; ++p) {
    const int c = p * 256 + tid, cc = c & 15;
    *(v8bf*)(As + (cc >> 2) * 4096 + (c >> 4) * 32 + (cc & 3) * 8) = av[p];
  }
#pragma unroll
  for (int p = 0; p < 4; ++p) {
    const int c = p * 256 + tid, cc = c & 15;
    *(v8bf*)(Bs + (cc >> 2) * 2048 + (c >> 4) * 32 + (cc & 3) * 8) = bv[p];
  }
}

__global__ __launch_bounds__(256) void k_pv(const short* __restrict__ E,
                                            const short* __restrict__ vT,  // [1024][8192]
                                            const float* __restrict__ l,
                                            short* __restrict__ attn) {
  __shared__ short As[16384];  // 4 sub-tiles [128][32]
  __shared__ short Bs[8192];   // 4 sub-tiles [64][32]
  const int tid = threadIdx.x, lane = tid & 63, wave = tid >> 6;
  const int wm = wave >> 1, wn = wave & 1;
  const int bx = (int)blockIdx.x;       // 0..31
  const int n0 = (int)blockIdx.y * 64;  // 0..15
  const int qd = lane >> 4, r16 = lane & 15;
  for (int half = 0; half < 2; ++half) {
    const int I = half ? 63 - bx : bx;
    const int m0 = I * 128;
    const short* Erow = E + (size_t)(I * (I + 1) / 2) * 16384;
    const short* vb = vT + (size_t)n0 * 8192;
    v4f acc[4][2];
#pragma unroll
    for (int mt = 0; mt < 4; ++mt)
#pragma unroll
      for (int nt = 0; nt < 2; ++nt) acc[mt][nt] = (v4f){0.f, 0.f, 0.f, 0.f};
    v8bf av[8], bv[4];
    pv_load(Erow, vb, av, bv, tid);
    __syncthreads();  // previous half's LDS reads done
    pv_write(As, Bs, av, bv, tid);
    __syncthreads();
    for (int J = 0; J <= I; ++J) {
      const bool more = (J < I);
      if (more) pv_load(Erow + (size_t)(J + 1) * 16384, vb + (J + 1) * 128, av, bv, tid);
#pragma unroll
      for (int jj = 0; jj < 4; ++jj) {
        const short* ab = As + jj * 4096 + (wm * 64 + r16) * 32 + qd * 8;
        const short* bb = Bs + jj * 2048 + (wn * 32 + r16) * 32 + qd * 8;
        v8bf a[4], b[2];
#pragma unroll
        for (int u = 0; u < 4; ++u) a[u] = *(const v8bf*)(ab + u * 512);
#pragma unroll
        for (int u = 0; u < 2; ++u) b[u] = *(const v8bf*)(bb + u * 512);
#pragma unroll
        for (int mt = 0; mt < 4; ++mt)
#pragma unroll
          for (int nt = 0; nt < 2; ++nt)
            acc[mt][nt] = __builtin_amdgcn_mfma_f32_16x16x32_bf16(a[mt], b[nt], acc[mt][nt], 0, 0, 0);
      }
      if (more) {
        __syncthreads();
        pv_write(As, Bs, av, bv, tid);
        __syncthreads();
      }
    }
    const int c16 = lane & 15;
#pragma unroll
    for (int mt = 0; mt < 4; ++mt) {
      const int rl = wm * 64 + mt * 16 + qd * 4;
      float inv[4];
#pragma unroll
      for (int r = 0; r < 4; ++r) inv[r] = 1.0f / fmaxf(l[m0 + rl + r], 1e-30f);
#pragma unroll
      for (int nt = 0; nt < 2; ++nt) {
        const int cl = wn * 32 + nt * 16 + c16;
#pragma unroll
        for (int r = 0; r < 4; ++r)
          attn[(size_t)(m0 + rl + r) * 1024 + n0 + cl] = f2bf(acc[mt][nt][r] * inv[r]);
      }
    }
  }
}

// ---------------------------------------------------------------------------
// GEMM2: out = attn[8192][1024] @ Wout + bout  -- FLOAT32 output
__global__ __launch_bounds__(256) void k_gemm_out(const short* __restrict__ attn,
                                                  const short* __restrict__ wt,  // [1024][1024] = Wout^T
                                                  const float* __restrict__ bout,
                                                  float* __restrict__ out) {
  __shared__ short As[4096], Bs[4096];
  const int tid = threadIdx.x, lane = tid & 63, wave = tid >> 6;
  const int wm = wave >> 1, wn = wave & 1;
  const int m0 = blockIdx.x * 128, n0 = blockIdx.y * 128;
  v4f acc[4][4];
  ACC_INIT(acc)
  for (int k0 = 0; k0 < 1024; k0 += 32) {
    __syncthreads();
    stage_tile(attn + (size_t)m0 * 1024 + k0, 1024, As, tid);
    stage_tile(wt + (size_t)n0 * 1024 + k0, 1024, Bs, tid);
    __syncthreads();
    mma_step(As, Bs, acc, lane, wm, wn);
  }
  const int qd = lane >> 4, c16 = lane & 15;
#pragma unroll
  for (int mt = 0; mt < 4; ++mt) {
    const int rl = wm * 64 + mt * 16 + qd * 4;
#pragma unroll
    for (int nt = 0; nt < 4; ++nt) {
      const int cl = wn * 64 + nt * 16 + c16;
      const float bias = bout[n0 + cl];
#pragma unroll
      for (int r = 0; r < 4; ++r)
        out[(size_t)(m0 + rl + r) * 1024 + n0 + cl] = acc[mt][nt][r] + bias;
    }
  }
}

// ---------------------------------------------------------------------------
extern "C" void kernel_launch(void* const* d_in, const int* in_sizes, int n_in,
                              void* d_out, int out_size, void* d_ws, size_t ws_size,
                              hipStream_t stream) {
  (void)out_size; (void)ws_size;
  const void *x = d_in[0], *Wqkv = d_in[1], *Wout = d_in[2], *bout = d_in[3];
  for (int i = 0; i < n_in; ++i) {
    switch (in_sizes[i]) {
      case 8192 * 1024: x = d_in[i]; break;
      case 1024 * 3072: Wqkv = d_in[i]; break;
      case 1024 * 1024: Wout = d_in[i]; break;
      case 1024:        bout = d_in[i]; break;
      default: break;
    }
  }

  char* ws = (char*)d_ws;
  short* qk    = (short*)(ws);                // 8192x2048 bf16 (q | k)   33.55 MB
  short* vT    = (short*)(ws + 33554432);     // 1024x8192 bf16           16.78 MB
  short* E     = (short*)(ws + 50331648);     // 2080 tiles of 128x128    68.16 MB
  short* xb    = (short*)(ws + 118489088);    // 8192x1024 bf16           16.78 MB
  short* attn  = xb;                          //   xb dead after GEMM1
  short* WqT   = (short*)(ws + 135266304);    // 3072x1024 bf16            6.29 MB
  short* WoT   = (short*)(ws + 141557760);    // 1024x1024 bf16            2.10 MB
  float* boutf = (float*)(ws + 143654912);    // 1024 fp32
  float* lsum  = (float*)(ws + 143659008);    // 8192 fp32 softmax denominators
  int*   flag  = (int*)  (ws + 143691776);    // dtype flag

  k_detect<<<1, 256, 0, stream>>>((const unsigned short*)x, flag);
  k_zerof<<<32, 256, 0, stream>>>(lsum, 8192);
  k_convert<<<1024, 256, 0, stream>>>(x, xb, 8192 * 1024, flag);
  k_to_f32<<<1, 256, 0, stream>>>(bout, boutf, 1024, flag);
  k_convT<<<dim3(96, 32), 256, 0, stream>>>(Wqkv, WqT, 1024, 3072, flag);
  k_convT<<<dim3(32, 32), 256, 0, stream>>>(Wout, WoT, 1024, 1024, flag);
  k_gemm_qkv<<<dim3(64, 24), 256, 0, stream>>>(xb, WqT, qk, vT);
  k_qk_exp<<<dim3(2080), 256, 0, stream>>>(qk, E, lsum);
  k_pv<<<dim3(32, 16), 256, 0, stream>>>(E, vT, lsum, attn);
  k_gemm_out<<<dim3(64, 8), 256, 0, stream>>>(attn, WoT, boutf, (float*)d_out);
}